// Round 7
// baseline (193.969 us; speedup 1.0000x reference)
//
#include <hip/hip_runtime.h>

// B=64, L=512, D=768, V=100
// summed[b,l,:] = w0s * pooler[b,l,:] + w1s * xt[b,:]
//   xt[b,d] = e0*W[0,d] + e1*W[1,d] + b_dense[d],  (e0,e1) = emb_table[ids[b]]
//   s00 = p.p (row), s01 = p.xt (row), s11 = xt.xt (per b); S0 = sum p, S1 = sum xt
//   out = gamma*(a*p + (c*xt - m)) + beta,  a=w0s*rstd, c=w1s*rstd, m=mean*rstd
//
// History (kernel time):
// R0 1-row/wave + NT:            <58.4us  (best; tied by R7)
// R3 4-row serialized:            ~65us   compiler serialized rows
// R4/R5 loads-up-front (+LB(,4)): ~62us   compiler sank/remat'd 48-reg tile
// R6 two-pass:                    ~71us   +66% traffic
// R7 LDS stash, no barrier:      <58.4us  load-reuse decoupled, floor unmoved
// R8 plain stores vs NT:          ~63us   store path exonerated
// => all theories about WHICH phase stalls are dead. The invariant: one-shot
//    waves with load->use distance ~0; nothing independent covers the ~900cyc
//    miss. The 6.8TB/s fill kernel (9% occ, 4.7% VALU) is a long-lived
//    STREAMING wave — per-wave pipelining, not TLP, is what it has.
// R9: streaming wave, hand-skewed 2-stage pipeline over 8 rows/wave:
//    iter r: [issue loads row r] [epilogue row r-1: FMA+NT store from held
//    12-reg tile (R0 proved 1-row tile survives the butterfly at VGPR 60)]
//    [partials row r] [butterfly+exp row r]. Load->use distance = one body.
//    #pragma unroll 1 preserves the skew; 1024 blocks = 4096 waves = one
//    residency generation.

constexpr int Bc = 64;
constexpr int Lc = 512;
constexpr int Dc = 768;            // 192 float4 = 3 float4 per lane (wave64)
constexpr int NF4 = Dc / 4;        // 192
constexpr float LN_EPS = 1e-6f;
constexpr int WPB = 4;             // waves per block
constexpr int RPW = 8;             // rows streamed per wave (8 | 512 -> one b)
constexpr int RPB = WPB * RPW;     // 32 rows per block

typedef float nv_float4 __attribute__((ext_vector_type(4)));

__global__ __launch_bounds__(64 * WPB, 4) void hier_attn_ln_kernel(
    const int*   __restrict__ ids,        // (B,1)
    const float* __restrict__ pooler,     // (B,L,D)
    const float* __restrict__ emb_table,  // (V,2)
    const float* __restrict__ W,          // (2,D)
    const float* __restrict__ bvec,       // (D,)
    const float* __restrict__ gamma,      // (D,)
    const float* __restrict__ beta,      // (D,)
    float*       __restrict__ out)        // (B,L,D)
{
    const int wave = threadIdx.x >> 6;
    const int lane = threadIdx.x & 63;
    const int wid  = blockIdx.x * WPB + wave;       // 0..4095
    const int row0 = wid * RPW;                     // 8 consecutive rows
    const int b    = row0 >> 9;                     // L=512; 8|512 -> one b

    const float4* W0_4 = (const float4*)W;
    const float4* W1_4 = (const float4*)(W + Dc);
    const float4* b_4  = (const float4*)bvec;
    const float4* g_4  = (const float4*)gamma;
    const float4* be_4 = (const float4*)beta;

    const int id = ids[b];
    const float e0 = emb_table[id * 2 + 0];
    const float e1 = emb_table[id * 2 + 1];

    // ---- loop invariants in registers: xt, gamma, beta (36 VGPR) ----
    float4 xt[3], gm[3], bt[3];
    float s11 = 0.f, S1 = 0.f;
#pragma unroll
    for (int j = 0; j < 3; ++j) {
        const int i4 = lane + j * 64;
        float4 w0 = W0_4[i4], w1 = W1_4[i4], bd = b_4[i4];
        gm[j] = g_4[i4];
        bt[j] = be_4[i4];
        float4 x;
        x.x = fmaf(e0, w0.x, fmaf(e1, w1.x, bd.x));
        x.y = fmaf(e0, w0.y, fmaf(e1, w1.y, bd.y));
        x.z = fmaf(e0, w0.z, fmaf(e1, w1.z, bd.z));
        x.w = fmaf(e0, w0.w, fmaf(e1, w1.w, bd.w));
        xt[j] = x;
        s11 += x.x*x.x + x.y*x.y + x.z*x.z + x.w*x.w;
        S1  += x.x + x.y + x.z + x.w;
    }
#pragma unroll
    for (int off = 32; off > 0; off >>= 1) {
        s11 += __shfl_xor(s11, off);
        S1  += __shfl_xor(S1,  off);
    }

    const float invD = 1.f / (float)Dc;
    const float4* p_base = (const float4*)(pooler + (size_t)row0 * Dc);
    nv_float4*    o_base = (nv_float4*)(out + (size_t)row0 * Dc);

    float4 pp[3];                 // held tile of the row whose scalars are done
    float pa, pc, pm;             // that row's LN scalars

    // ---- prologue: row 0 partials -> butterfly -> scalars ----
    {
        float a0 = 0.f, a1 = 0.f, a2 = 0.f;
#pragma unroll
        for (int j = 0; j < 3; ++j) {
            const float4 q = p_base[lane + j * 64];
            pp[j] = q;
            a0 += q.x*q.x + q.y*q.y + q.z*q.z + q.w*q.w;
            a1 += q.x*xt[j].x + q.y*xt[j].y + q.z*xt[j].z + q.w*xt[j].w;
            a2 += q.x + q.y + q.z + q.w;
        }
#pragma unroll
        for (int off = 32; off > 0; off >>= 1) {
            a0 += __shfl_xor(a0, off);
            a1 += __shfl_xor(a1, off);
            a2 += __shfl_xor(a2, off);
        }
        // Two 2-way softmaxes (max-subtracted: s00 ~ O(768), exp overflows raw).
        const float m0  = fmaxf(a0, a1);
        const float x00 = __expf(a0 - m0);
        const float x01 = __expf(a1 - m0);
        const float r0  = 1.f / (x00 + x01);
        const float m1  = fmaxf(a1, s11);
        const float x10 = __expf(a1 - m1);
        const float x11 = __expf(s11 - m1);
        const float r1  = 1.f / (x10 + x11);
        const float w0s = x00 * r0 + x10 * r1;
        const float w1s = x01 * r0 + x11 * r1;
        const float mean = (w0s * a2 + w1s * S1) * invD;
        const float ex2  = (w0s*w0s*a0 + 2.f*w0s*w1s*a1 + w1s*w1s*s11) * invD;
        const float rstd = rsqrtf(ex2 - mean * mean + LN_EPS);
        pa = w0s * rstd; pc = w1s * rstd; pm = mean * rstd;
    }

    // ---- skewed steady state: loads(r) || epilogue(r-1) || reduce(r) ----
#pragma unroll 1
    for (int r = 1; r < RPW; ++r) {
        // (1) issue row-r loads; land one full body later
        const float4 q0 = p_base[r * NF4 + lane];
        const float4 q1 = p_base[r * NF4 + lane + 64];
        const float4 q2 = p_base[r * NF4 + lane + 128];

        // (2) epilogue row r-1: independent of q* -> executes in load shadow
        {
            nv_float4* orow = o_base + (size_t)(r - 1) * NF4;
#pragma unroll
            for (int j = 0; j < 3; ++j) {
                const float4 p = pp[j];
                nv_float4 o;
                o.x = fmaf(gm[j].x, fmaf(pa, p.x, fmaf(pc, xt[j].x, -pm)), bt[j].x);
                o.y = fmaf(gm[j].y, fmaf(pa, p.y, fmaf(pc, xt[j].y, -pm)), bt[j].y);
                o.z = fmaf(gm[j].z, fmaf(pa, p.z, fmaf(pc, xt[j].z, -pm)), bt[j].z);
                o.w = fmaf(gm[j].w, fmaf(pa, p.w, fmaf(pc, xt[j].w, -pm)), bt[j].w);
                __builtin_nontemporal_store(o, &orow[lane + j * 64]);
            }
        }

        // (3) partials row r (first true use of q*); tile rotates pp <- q
        float a0, a1, a2;
        {
            a0  = q0.x*q0.x + q0.y*q0.y + q0.z*q0.z + q0.w*q0.w;
            a1  = q0.x*xt[0].x + q0.y*xt[0].y + q0.z*xt[0].z + q0.w*xt[0].w;
            a2  = q0.x + q0.y + q0.z + q0.w;
            a0 += q1.x*q1.x + q1.y*q1.y + q1.z*q1.z + q1.w*q1.w;
            a1 += q1.x*xt[1].x + q1.y*xt[1].y + q1.z*xt[1].z + q1.w*xt[1].w;
            a2 += q1.x + q1.y + q1.z + q1.w;
            a0 += q2.x*q2.x + q2.y*q2.y + q2.z*q2.z + q2.w*q2.w;
            a1 += q2.x*xt[2].x + q2.y*xt[2].y + q2.z*xt[2].z + q2.w*xt[2].w;
            a2 += q2.x + q2.y + q2.z + q2.w;
            pp[0] = q0; pp[1] = q1; pp[2] = q2;
        }

        // (4) butterfly + softmax + LN scalars for row r
#pragma unroll
        for (int off = 32; off > 0; off >>= 1) {
            a0 += __shfl_xor(a0, off);
            a1 += __shfl_xor(a1, off);
            a2 += __shfl_xor(a2, off);
        }
        const float m0  = fmaxf(a0, a1);
        const float x00 = __expf(a0 - m0);
        const float x01 = __expf(a1 - m0);
        const float r0  = 1.f / (x00 + x01);
        const float m1  = fmaxf(a1, s11);
        const float x10 = __expf(a1 - m1);
        const float x11 = __expf(s11 - m1);
        const float r1  = 1.f / (x10 + x11);
        const float w0s = x00 * r0 + x10 * r1;
        const float w1s = x01 * r0 + x11 * r1;
        const float mean = (w0s * a2 + w1s * S1) * invD;
        const float ex2  = (w0s*w0s*a0 + 2.f*w0s*w1s*a1 + w1s*w1s*s11) * invD;
        const float rstd = rsqrtf(ex2 - mean * mean + LN_EPS);
        pa = w0s * rstd; pc = w1s * rstd; pm = mean * rstd;
    }

    // ---- drain: epilogue of the last row ----
    {
        nv_float4* orow = o_base + (size_t)(RPW - 1) * NF4;
#pragma unroll
        for (int j = 0; j < 3; ++j) {
            const float4 p = pp[j];
            nv_float4 o;
            o.x = fmaf(gm[j].x, fmaf(pa, p.x, fmaf(pc, xt[j].x, -pm)), bt[j].x);
            o.y = fmaf(gm[j].y, fmaf(pa, p.y, fmaf(pc, xt[j].y, -pm)), bt[j].y);
            o.z = fmaf(gm[j].z, fmaf(pa, p.z, fmaf(pc, xt[j].z, -pm)), bt[j].z);
            o.w = fmaf(gm[j].w, fmaf(pa, p.w, fmaf(pc, xt[j].w, -pm)), bt[j].w);
            __builtin_nontemporal_store(o, &orow[lane + j * 64]);
        }
    }
}

extern "C" void kernel_launch(void* const* d_in, const int* in_sizes, int n_in,
                              void* d_out, int out_size, void* d_ws, size_t ws_size,
                              hipStream_t stream) {
    const int*   ids       = (const int*)  d_in[0];
    const float* pooler    = (const float*)d_in[1];
    const float* emb_table = (const float*)d_in[2];
    const float* W_dense   = (const float*)d_in[3];
    const float* b_dense   = (const float*)d_in[4];
    const float* gamma     = (const float*)d_in[5];
    const float* beta      = (const float*)d_in[6];
    float* out = (float*)d_out;

    const int nrows = Bc * Lc;                      // 32768
    hipLaunchKernelGGL(hier_attn_ln_kernel,
                       dim3(nrows / RPB), dim3(64 * WPB),   // 1024 blocks
                       0, stream,
                       ids, pooler, emb_table, W_dense, b_dense, gamma, beta, out);
}